// Round 20
// baseline (91.681 us; speedup 1.0000x reference)
//
#include <hip/hip_runtime.h>
#include <hip/hip_bf16.h>

// WaveNet single-output inference on MI355X — v14: fuseB inlined into fuseA via
// last-block-per-batch handoff (device-scope atomic counter + threadfence).
// Sparse tree: only skip_sum[:, :, 8190] matters; per-layer needed positions
// form APs with stride dilation/2; h_12 never needed.
// fuseA: block (4 waves) owns one chunk's in_conv + layers 0-5 pyramid
//        (96->95->47->23->11->5->2); tiles split across waves, 1 barrier/layer.
//        After writing c6, each block increments cnt[b]; the 32nd block runs
//        the former fuseB (layers 6-11 + skip + head) inline, reusing its LDS.
// Residual: 2 ds_read_b128 + 4 identity-MFMAs into res-GEMM C-init (bit-exact;
// r18/r19 passed absmax 0.0 with this path).

typedef __attribute__((ext_vector_type(8))) short short8;
typedef __attribute__((ext_vector_type(4))) float f32x4;

#define TLAST 8190
#define BATCH 32
#define MFMA(A, B, C) __builtin_amdgcn_mfma_f32_16x16x32_bf16(A, B, C, 0, 0, 0)

__device__ __forceinline__ ushort cvtb(float x) {
    union { __hip_bfloat16 b; ushort u; } c;
    c.b = __float2bfloat16(x);
    return c.u;
}
__device__ __forceinline__ float bf2f(ushort h) {
    return __uint_as_float((uint)h << 16);
}
__device__ __forceinline__ void split2(float v, ushort& h, ushort& l) {
    h = cvtb(v);
    l = cvtb(v - bf2f(h));
}
__device__ __forceinline__ int imin(int a, int b) { return a < b ? a : b; }
__device__ __forceinline__ float act_native(float gate, float filt) {
    const float e1 = __builtin_amdgcn_exp2f(filt * 2.885390082f);    // e^{2f}
    const float e2 = __builtin_amdgcn_exp2f(gate * -1.442695041f);   // e^{-g}
    return (e1 - 1.f) * __builtin_amdgcn_rcpf((e1 + 1.f) * (1.f + e2));
}
// identity B-fragment for (nl, o), col n = nl + 16*nt: slot j is k = 8o+j
__device__ __forceinline__ short8 ident_frag(int nl, int o, int nt) {
    short8 v = {0, 0, 0, 0, 0, 0, 0, 0};
    #pragma unroll
    for (int j = 0; j < 8; ++j)
        v[j] = (8 * o + j == nl + 16 * nt) ? (short)0x3F80 : (short)0;
    return v;
}

// ---------------------------------------------------------------- weight prep
// Frag-major bf16: dil k = ic + 32*kt, lane = o*16+nl,
// frag (a,kt,nt) at Wd[l*8192 + ((kt*4+nt)*2+a)*512 + lane*8 + (k&7)], a:0=h 1=lo.
// Also zeroes the 32 per-batch completion counters.
__global__ __launch_bounds__(256) void wn_prep(
    const float* __restrict__ dil_w, const float* __restrict__ res_w,
    ushort* __restrict__ Wd, ushort* __restrict__ Wr, uint* __restrict__ cnt)
{
    const int idx = blockIdx.x * 256 + threadIdx.x;
    if (blockIdx.x == 0 && threadIdx.x < BATCH) cnt[threadIdx.x] = 0u;
    if (idx < 12 * 4096) {
        const int l = idx >> 12, rem = idx & 4095, n = rem >> 6, k = rem & 63;
        const int kt = k >> 5, ic = k & 31, o = (k >> 3) & 3, r8 = k & 7;
        const int lane = o * 16 + (n & 15), nt = n >> 4;
        const float v = dil_w[((size_t)l * 64 + n) * 64 + 2 * ic + kt];
        ushort h, lo;
        split2(v, h, lo);
        const int base = l * 8192 + ((kt * 4 + nt) * 2) * 512 + lane * 8 + r8;
        Wd[base] = h;
        Wd[base + 512] = lo;
    } else if (idx < 12 * 4096 + 12 * 1024) {
        const int j = idx - 12 * 4096;
        const int l = j >> 10, rem = j & 1023, n = rem >> 5, k = rem & 31;
        const int o = k >> 3, r8 = k & 7;
        const int lane = o * 16 + (n & 15), nt = n >> 4;
        ushort h, lo;
        split2(res_w[j], h, lo);
        const int base = l * 2048 + (nt * 2) * 512 + lane * 8 + r8;
        Wr[base] = h;
        Wr[base + 512] = lo;
    }
}

// ---------------------------------------------------------------- tile body
// (used by the inline fuseB tail; identical math to r19's layer_tile1)
__device__ __forceinline__ void layer_tile1(
    const ushort* __restrict__ HiH, const ushort* __restrict__ HiL,
    ushort* __restrict__ HoH, ushort* __restrict__ HoL,
    const ushort* __restrict__ pd, const ushort* __restrict__ pr,
    const float* __restrict__ db, const float* __restrict__ rb,
    float* __restrict__ gout, ushort* __restrict__ sGH, ushort* __restrict__ sGL,
    int tt, int nIn, int nOut, int sO, int aO, int bOff,
    int lane, int nl, int o, int doRes)
{
    const short8 z8 = {0,0,0,0,0,0,0,0};
    const int joF = tt * 16 + nl;
    const int j0 = imin(2 * joF, nIn - 1);
    const int j1 = imin(2 * joF + 2, nIn - 1);
    const int jr = imin(2 * joF + 1, nIn - 1);
    const bool zB = (aO + joF * sO + bOff) > TLAST;

    float dbg[2], dbf[2], rbv[2];
    #pragma unroll
    for (int nt = 0; nt < 2; ++nt) {
        dbg[nt] = db[nl + 16 * nt];
        dbf[nt] = db[nl + 16 * nt + 32];
        rbv[nt] = rb[nl + 16 * nt];
    }

    const short8 I0 = ident_frag(nl, o, 0);
    const short8 I1 = ident_frag(nl, o, 1);
    const short8 RhA = *(const short8*)&HiH[jr * 40 + 8 * o];
    const short8 RlA = *(const short8*)&HiL[jr * 40 + 8 * o];
    f32x4 aR[2];
    aR[0] = (f32x4){rbv[0], rbv[0], rbv[0], rbv[0]};
    aR[1] = (f32x4){rbv[1], rbv[1], rbv[1], rbv[1]};
    aR[0] = MFMA(RhA, I0, aR[0]);
    aR[0] = MFMA(RlA, I0, aR[0]);
    aR[1] = MFMA(RhA, I1, aR[1]);
    aR[1] = MFMA(RlA, I1, aR[1]);

    short8 Ah[2], Al[2];
    Ah[0] = *(const short8*)&HiH[j0 * 40 + 8 * o];
    Al[0] = *(const short8*)&HiL[j0 * 40 + 8 * o];
    if (zB) { Ah[1] = z8; Al[1] = z8; }
    else {
        Ah[1] = *(const short8*)&HiH[j1 * 40 + 8 * o];
        Al[1] = *(const short8*)&HiL[j1 * 40 + 8 * o];
    }

    f32x4 acc[4];
    #pragma unroll
    for (int nt = 0; nt < 2; ++nt) {
        acc[nt]     = (f32x4){dbg[nt], dbg[nt], dbg[nt], dbg[nt]};
        acc[nt + 2] = (f32x4){dbf[nt], dbf[nt], dbf[nt], dbf[nt]};
    }
    #pragma unroll
    for (int kt = 0; kt < 2; ++kt)
        #pragma unroll
        for (int nt = 0; nt < 4; ++nt) {
            const int base = ((kt * 4 + nt) * 2) * 512 + lane * 8;
            const short8 Bh = *(const short8*)&pd[base];
            const short8 Bl = *(const short8*)&pd[base + 512];
            acc[nt] = MFMA(Ah[kt], Bh, acc[nt]);
            acc[nt] = MFMA(Ah[kt], Bl, acc[nt]);
            acc[nt] = MFMA(Al[kt], Bh, acc[nt]);
        }

    const int capRem = TLAST - aO;
    const int capIdx = ((capRem % sO) == 0) ? (capRem / sO) : -1;
    float gv[8];
    #pragma unroll
    for (int nt = 0; nt < 2; ++nt)
        #pragma unroll
        for (int r = 0; r < 4; ++r) {
            const float g = act_native(acc[nt][r], acc[nt + 2][r]);
            gv[nt * 4 + r] = g;
            const int ml = 4 * o + r, n = nl + 16 * nt;
            ushort gh16, gl16;
            split2(g, gh16, gl16);
            sGH[ml * 40 + n] = gh16;
            sGL[ml * 40 + n] = gl16;
        }
    if (capIdx >= tt * 16 && capIdx < imin(tt * 16 + 16, nOut)) {
        #pragma unroll
        for (int nt = 0; nt < 2; ++nt)
            #pragma unroll
            for (int r = 0; r < 4; ++r)
                if (tt * 16 + 4 * o + r == capIdx)
                    gout[nl + 16 * nt] = gv[nt * 4 + r];
    }

    if (doRes) {
        const short8 gh = *(const short8*)&sGH[nl * 40 + 8 * o];
        const short8 gl = *(const short8*)&sGL[nl * 40 + 8 * o];
        #pragma unroll
        for (int nt = 0; nt < 2; ++nt) {
            const int base = (nt * 2) * 512 + lane * 8;
            const short8 Rh = *(const short8*)&pr[base];
            const short8 Rl = *(const short8*)&pr[base + 512];
            aR[nt] = MFMA(gh, Rh, aR[nt]);
            aR[nt] = MFMA(gh, Rl, aR[nt]);
            aR[nt] = MFMA(gl, Rh, aR[nt]);
        }
        #pragma unroll
        for (int nt = 0; nt < 2; ++nt)
            #pragma unroll
            for (int r = 0; r < 4; ++r) {
                const int joE = tt * 16 + 4 * o + r;
                if (joE < nOut) {
                    const int n = nl + 16 * nt;
                    ushort hh, hl;
                    split2(aR[nt][r], hh, hl);
                    HoH[joE * 40 + n] = hh;
                    HoL[joE * 40 + n] = hl;
                }
            }
    }
}

// ---------------------------------------------------------------- phase A+B
// Grid (32, BATCH), 4 waves. Pyramid rows: stride 40 ushorts (80 B).
__global__ __launch_bounds__(256) void wn_fuseA(
    const float* __restrict__ x, const float* __restrict__ in_w,
    const float* __restrict__ in_b,
    const ushort* __restrict__ Wd, const ushort* __restrict__ Wr,
    const float* __restrict__ dil_b, const float* __restrict__ res_b,
    ushort* __restrict__ c6h, ushort* __restrict__ c6l,
    float* __restrict__ gTL, uint* __restrict__ cnt,
    const float* __restrict__ sw, const float* __restrict__ sb,
    const float* __restrict__ f1w, const float* __restrict__ f1b,
    const float* __restrict__ f2w, const float* __restrict__ f2b,
    float* __restrict__ out)
{
    __shared__ __align__(16) ushort pingH[96 * 40], pingL[96 * 40];
    __shared__ __align__(16) ushort pongH[95 * 40], pongL[95 * 40];
    __shared__ __align__(16) ushort sGH[4][16 * 40], sGL[4][16 * 40];
    __shared__ float gcap[6 * 32];
    __shared__ float psum[4][32];
    __shared__ float hd[64];
    __shared__ int lastFlag;
    float* xs = (float*)pongH;                   // 7680 B, fits pongH

    const int tid = threadIdx.x, lane = tid & 63, w = tid >> 6;
    const int nl = lane & 15, o = lane >> 4;
    const int cc = blockIdx.x, b = blockIdx.y;
    const int t6a = 6174 + cc * 64, a0 = t6a - 31;
    const short8 z8 = {0, 0, 0, 0, 0, 0, 0, 0};
    const short8 I0 = ident_frag(nl, o, 0);
    const short8 I1 = ident_frag(nl, o, 1);

    // ---- stage x (96 pos x 16 ch fp32)
    for (int i = tid; i < 384; i += 256) {
        const int p = i >> 2, c4 = (i & 3) * 4;
        const int t = a0 + p;
        float4 v = make_float4(0.f, 0.f, 0.f, 0.f);
        if (t <= 8191) v = *(const float4*)&x[((size_t)b * 8192 + t) * 16 + c4];
        *(float4*)&xs[p * 20 + c4] = v;
    }
    __syncthreads();

    // ---- in_conv -> ping (hi/lo)
    {
        const int c = tid & 31, pg = tid >> 5;
        float wr[16];
        #pragma unroll
        for (int f = 0; f < 16; ++f) wr[f] = in_w[c * 16 + f];
        const float bias = in_b[c];
        #pragma unroll
        for (int q = 0; q < 12; ++q) {
            const int p = pg + 8 * q;
            float acc = bias;
            #pragma unroll
            for (int f4 = 0; f4 < 4; ++f4) {
                const float4 xv = *(const float4*)&xs[p * 20 + f4 * 4];
                acc += wr[f4*4]*xv.x + wr[f4*4+1]*xv.y
                     + wr[f4*4+2]*xv.z + wr[f4*4+3]*xv.w;
            }
            ushort hh, hl;
            split2(acc, hh, hl);
            pingH[p * 40 + c] = hh;
            pingL[p * 40 + c] = hl;
        }
    }
    __syncthreads();   // xs dead; pong free for l0 output

    for (int l = 0; l < 6; ++l) {
        const ushort* HiH = (l & 1) ? pongH : pingH;
        const ushort* HiL = (l & 1) ? pongL : pingL;
        ushort* HoH = (l & 1) ? pingH : pongH;
        ushort* HoL = (l & 1) ? pingL : pongL;
        const int nIn  = (l == 0) ? 96 : (192 >> l) - 1;
        const int nOut = (192 >> (l + 1)) - 1;      // 95,47,23,11,5,2
        const int nT   = (nOut + 15) >> 4;
        const int sO   = 1 << l;
        const int aO   = a0 + sO - 1;
        const int bOff = (l == 0) ? 1 : (sO >> 1);
        const int rmx  = (l == 0) ? 8191 : TLAST;
        const int first = (l == 0);
        const int capRem = TLAST - aO;
        const int capIdx = ((capRem % sO) == 0) ? (capRem / sO) : -1;

        const ushort* pd = Wd + (size_t)l * 8192;
        const ushort* pr = Wr + (size_t)l * 2048;
        float dbg[2], dbf[2], rbv[2];
        #pragma unroll
        for (int nt = 0; nt < 2; ++nt) {
            dbg[nt] = dil_b[l * 64 + nl + 16 * nt];
            dbf[nt] = dil_b[l * 64 + nl + 16 * nt + 32];
            rbv[nt] = res_b[l * 32 + nl + 16 * nt];
        }

        for (int tt = w; tt < nT; tt += 4) {
            const int joF = tt * 16 + nl;
            const int j0 = imin(first ? joF : 2 * joF, nIn - 1);
            const int j1 = imin(first ? joF + 1 : 2 * joF + 2, nIn - 1);
            const int jr = imin(first ? joF + 1 : 2 * joF + 1, nIn - 1);
            const bool zB = (aO + joF * sO + bOff) > rmx;

            const short8 RhA = *(const short8*)&HiH[jr * 40 + 8 * o];
            const short8 RlA = *(const short8*)&HiL[jr * 40 + 8 * o];
            f32x4 aR[2];
            aR[0] = (f32x4){rbv[0], rbv[0], rbv[0], rbv[0]};
            aR[1] = (f32x4){rbv[1], rbv[1], rbv[1], rbv[1]};
            aR[0] = MFMA(RhA, I0, aR[0]);
            aR[0] = MFMA(RlA, I0, aR[0]);
            aR[1] = MFMA(RhA, I1, aR[1]);
            aR[1] = MFMA(RlA, I1, aR[1]);

            short8 Ah[2], Al[2];
            Ah[0] = *(const short8*)&HiH[j0 * 40 + 8 * o];
            Al[0] = *(const short8*)&HiL[j0 * 40 + 8 * o];
            if (zB) { Ah[1] = z8; Al[1] = z8; }
            else {
                Ah[1] = *(const short8*)&HiH[j1 * 40 + 8 * o];
                Al[1] = *(const short8*)&HiL[j1 * 40 + 8 * o];
            }

            f32x4 acc[4];
            #pragma unroll
            for (int nt = 0; nt < 2; ++nt) {
                acc[nt]     = (f32x4){dbg[nt], dbg[nt], dbg[nt], dbg[nt]};
                acc[nt + 2] = (f32x4){dbf[nt], dbf[nt], dbf[nt], dbf[nt]};
            }
            #pragma unroll
            for (int kt = 0; kt < 2; ++kt)
                #pragma unroll
                for (int nt = 0; nt < 4; ++nt) {
                    const int base = ((kt * 4 + nt) * 2) * 512 + lane * 8;
                    const short8 Bh = *(const short8*)&pd[base];
                    const short8 Bl = *(const short8*)&pd[base + 512];
                    acc[nt] = MFMA(Ah[kt], Bh, acc[nt]);
                    acc[nt] = MFMA(Ah[kt], Bl, acc[nt]);
                    acc[nt] = MFMA(Al[kt], Bh, acc[nt]);
                }

            float gv[8];
            #pragma unroll
            for (int nt = 0; nt < 2; ++nt)
                #pragma unroll
                for (int r = 0; r < 4; ++r) {
                    const float g = act_native(acc[nt][r], acc[nt + 2][r]);
                    gv[nt * 4 + r] = g;
                    const int ml = 4 * o + r, n = nl + 16 * nt;
                    ushort gh16, gl16;
                    split2(g, gh16, gl16);
                    sGH[w][ml * 40 + n] = gh16;
                    sGL[w][ml * 40 + n] = gl16;
                }
            if (capIdx >= tt * 16 && capIdx < imin(tt * 16 + 16, nOut)) {
                #pragma unroll
                for (int nt = 0; nt < 2; ++nt)
                    #pragma unroll
                    for (int r = 0; r < 4; ++r)
                        if (tt * 16 + 4 * o + r == capIdx)
                            gTL[((size_t)l * BATCH + b) * 32 + nl + 16 * nt] =
                                gv[nt * 4 + r];
            }

            const short8 gh = *(const short8*)&sGH[w][nl * 40 + 8 * o];
            const short8 gl = *(const short8*)&sGL[w][nl * 40 + 8 * o];
            #pragma unroll
            for (int nt = 0; nt < 2; ++nt) {
                const int base = (nt * 2) * 512 + lane * 8;
                const short8 Rh = *(const short8*)&pr[base];
                const short8 Rl = *(const short8*)&pr[base + 512];
                aR[nt] = MFMA(gh, Rh, aR[nt]);
                aR[nt] = MFMA(gh, Rl, aR[nt]);
                aR[nt] = MFMA(gl, Rh, aR[nt]);
            }
            #pragma unroll
            for (int nt = 0; nt < 2; ++nt)
                #pragma unroll
                for (int r = 0; r < 4; ++r) {
                    const int joE = tt * 16 + 4 * o + r;
                    if (joE < nOut) {
                        const int n = nl + 16 * nt;
                        ushort hh, hl;
                        split2(aR[nt][r], hh, hl);
                        HoH[joE * 40 + n] = hh;
                        HoL[joE * 40 + n] = hl;
                        if (l == 5 && joE < 2) {
                            const size_t go = ((size_t)b * 64 + cc * 2 + joE) * 32 + n;
                            c6h[go] = hh;
                            c6l[go] = hl;
                        }
                    }
                }
        }
        __syncthreads();
    }

    // ---- last-block-per-batch handoff (no spinning; 32nd block continues)
    if (tid == 0) {
        __threadfence();                       // publish this block's c6/gTL
        const uint old = atomicAdd(&cnt[b], 1u);
        lastFlag = (old == BATCH - 1u) ? 1 : 0;
    }
    __syncthreads();
    if (!lastFlag) return;
    __threadfence();                           // acquire other blocks' c6/gTL

    // ================= inline fuseB for batch b =================
    // Reuse LDS: HA -> ping, HB -> pong, sG2 -> sGH/sGL[0..1].
    ushort* HAh = pingH;  ushort* HAl = pingL;
    ushort* HBh = pongH;  ushort* HBl = pongL;

    for (int i = tid; i < 256; i += 256) {
        const int row = i >> 2, c8 = (i & 3) * 8;
        *(short8*)&HAh[row * 40 + c8] = *(const short8*)&c6h[((size_t)b * 64 + row) * 32 + c8];
        *(short8*)&HAl[row * 40 + c8] = *(const short8*)&c6l[((size_t)b * 64 + row) * 32 + c8];
    }
    __syncthreads();

    if (w < 2) {
        layer_tile1(HAh, HAl, HBh, HBl, Wd + 6 * 8192, Wr + 6 * 2048,
                    dil_b + 6 * 64, res_b + 6 * 32,
                    gcap, sGH[w], sGL[w],
                    w, 64, 32, 64, 6206, 32, lane, nl, o, 1);
    }
    __syncthreads();

    if (w == 0) {
        for (int ll = 1; ll < 6; ++ll) {
            const int l = ll + 6;
            const ushort* HiH = (ll & 1) ? HBh : HAh;
            const ushort* HiL = (ll & 1) ? HBl : HAl;
            ushort* HoH = (ll & 1) ? HAh : HBh;
            ushort* HoL = (ll & 1) ? HAl : HBl;
            const int sO = 64 << ll;
            layer_tile1(HiH, HiL, HoH, HoL,
                        Wd + (size_t)l * 8192, Wr + (size_t)l * 2048,
                        dil_b + l * 64, res_b + l * 32,
                        gcap + ll * 32, sGH[0], sGL[0],
                        0, 64 >> ll, 32 >> ll, sO, 6142 + sO, sO >> 1,
                        lane, nl, o, (ll < 5) ? 1 : 0);
        }
    }
    __syncthreads();

    if (lane < 32) {
        const int c = lane;
        float part = 0.f;
        #pragma unroll
        for (int j = 0; j < 3; ++j) {
            const int l2 = 3 * w + j;
            float a = sb[l2 * 32 + c];
            const float* swr = sw + l2 * 1024 + c * 32;
            const float* gvp = (l2 < 6) ? (gTL + ((size_t)l2 * BATCH + b) * 32)
                                        : (gcap + (l2 - 6) * 32);
            #pragma unroll
            for (int ic = 0; ic < 32; ++ic) a += swr[ic] * gvp[ic];
            part += a;
        }
        psum[w][c] = part;
    }
    __syncthreads();

    if (w == 0 && lane < 32)
        hd[lane] = fmaxf(psum[0][lane] + psum[1][lane] + psum[2][lane] + psum[3][lane], 0.f);
    if (w == 0 && lane < 32) {
        float z = f1b[lane];
        #pragma unroll
        for (int ic = 0; ic < 32; ++ic) z += f1w[lane * 32 + ic] * hd[ic];
        hd[32 + lane] = fmaxf(z, 0.f);
    }
    if (w == 0 && lane == 0) {
        float o2 = f2b[0];
        #pragma unroll
        for (int ic = 0; ic < 32; ++ic) o2 += f2w[ic] * hd[32 + ic];
        out[b] = o2;
    }
}

// ---------------------------------------------------------------- launch
extern "C" void kernel_launch(void* const* d_in, const int* in_sizes, int n_in,
                              void* d_out, int out_size, void* d_ws, size_t ws_size,
                              hipStream_t stream)
{
    const float* x      = (const float*)d_in[0];
    const float* in_w   = (const float*)d_in[1];
    const float* in_b   = (const float*)d_in[2];
    const float* dil_w  = (const float*)d_in[3];
    const float* dil_b  = (const float*)d_in[4];
    const float* skip_w = (const float*)d_in[5];
    const float* skip_b = (const float*)d_in[6];
    const float* res_w  = (const float*)d_in[7];
    const float* res_b  = (const float*)d_in[8];
    const float* f1_w   = (const float*)d_in[9];
    const float* f1_b   = (const float*)d_in[10];
    const float* f2_w   = (const float*)d_in[11];
    const float* f2_b   = (const float*)d_in[12];

    char* p = (char*)d_ws;
    ushort* Wd  = (ushort*)p; p += 12 * 8192 * 2;
    ushort* Wr  = (ushort*)p; p += 12 * 2048 * 2;
    ushort* c6h = (ushort*)p; p += 32 * 64 * 32 * 2;
    ushort* c6l = (ushort*)p; p += 32 * 64 * 32 * 2;
    float*  gTL = (float*)p;  p += 12 * 32 * 32 * 4;
    uint*   cnt = (uint*)p;

    wn_prep<<<dim3(240), dim3(256), 0, stream>>>(dil_w, res_w, Wd, Wr, cnt);

    wn_fuseA<<<dim3(32, BATCH), dim3(256), 0, stream>>>(
        x, in_w, in_b, Wd, Wr, dil_b, res_b, c6h, c6l, gTL, cnt,
        skip_w, skip_b, f1_w, f1_b, f2_w, f2_b, (float*)d_out);
}

// Round 21
// 57.316 us; speedup vs baseline: 1.5996x; 1.5996x over previous
//
#include <hip/hip_runtime.h>
#include <hip/hip_bf16.h>

// WaveNet single-output inference on MI355X — v13 (r19, best verified: 57.4us,
// absmax 0.0). Sparse tree: only skip_sum[:, :, 8190] matters; per-layer
// needed positions form APs with stride dilation/2; h_12 never needed.
// fuseA: block (4 waves) owns one chunk's in_conv + layers 0-5 pyramid
//        (96->95->47->23->11->5->2); tiles split across waves, 1 barrier/layer.
// fuseB: ll0 on 2 waves, ll1-5 wave 0, head split across 4 waves.
// Residual: 2 ds_read_b128 + 4 identity-MFMAs into res-GEMM C-init (bit-exact).
// r20's last-block fusion reverted: it raised VGPR 84->112 (occupancy loss for
// all blocks) and serialized the dispatch tail -> 91.7us regression.

typedef __attribute__((ext_vector_type(8))) short short8;
typedef __attribute__((ext_vector_type(4))) float f32x4;

#define TLAST 8190
#define BATCH 32
#define MFMA(A, B, C) __builtin_amdgcn_mfma_f32_16x16x32_bf16(A, B, C, 0, 0, 0)

__device__ __forceinline__ ushort cvtb(float x) {
    union { __hip_bfloat16 b; ushort u; } c;
    c.b = __float2bfloat16(x);
    return c.u;
}
__device__ __forceinline__ float bf2f(ushort h) {
    return __uint_as_float((uint)h << 16);
}
__device__ __forceinline__ void split2(float v, ushort& h, ushort& l) {
    h = cvtb(v);
    l = cvtb(v - bf2f(h));
}
__device__ __forceinline__ int imin(int a, int b) { return a < b ? a : b; }
__device__ __forceinline__ float act_native(float gate, float filt) {
    const float e1 = __builtin_amdgcn_exp2f(filt * 2.885390082f);    // e^{2f}
    const float e2 = __builtin_amdgcn_exp2f(gate * -1.442695041f);   // e^{-g}
    return (e1 - 1.f) * __builtin_amdgcn_rcpf((e1 + 1.f) * (1.f + e2));
}
// identity B-fragment for (nl, o), col n = nl + 16*nt: slot j is k = 8o+j
__device__ __forceinline__ short8 ident_frag(int nl, int o, int nt) {
    short8 v = {0, 0, 0, 0, 0, 0, 0, 0};
    #pragma unroll
    for (int j = 0; j < 8; ++j)
        v[j] = (8 * o + j == nl + 16 * nt) ? (short)0x3F80 : (short)0;
    return v;
}

// ---------------------------------------------------------------- weight prep
// Frag-major bf16: dil k = ic + 32*kt, lane = o*16+nl,
// frag (a,kt,nt) at Wd[l*8192 + ((kt*4+nt)*2+a)*512 + lane*8 + (k&7)], a:0=h 1=lo.
__global__ __launch_bounds__(256) void wn_prep(
    const float* __restrict__ dil_w, const float* __restrict__ res_w,
    ushort* __restrict__ Wd, ushort* __restrict__ Wr)
{
    const int idx = blockIdx.x * 256 + threadIdx.x;
    if (idx < 12 * 4096) {
        const int l = idx >> 12, rem = idx & 4095, n = rem >> 6, k = rem & 63;
        const int kt = k >> 5, ic = k & 31, o = (k >> 3) & 3, r8 = k & 7;
        const int lane = o * 16 + (n & 15), nt = n >> 4;
        const float v = dil_w[((size_t)l * 64 + n) * 64 + 2 * ic + kt];
        ushort h, lo;
        split2(v, h, lo);
        const int base = l * 8192 + ((kt * 4 + nt) * 2) * 512 + lane * 8 + r8;
        Wd[base] = h;
        Wd[base + 512] = lo;
    } else if (idx < 12 * 4096 + 12 * 1024) {
        const int j = idx - 12 * 4096;
        const int l = j >> 10, rem = j & 1023, n = rem >> 5, k = rem & 31;
        const int o = k >> 3, r8 = k & 7;
        const int lane = o * 16 + (n & 15), nt = n >> 4;
        ushort h, lo;
        split2(res_w[j], h, lo);
        const int base = l * 2048 + (nt * 2) * 512 + lane * 8 + r8;
        Wr[base] = h;
        Wr[base + 512] = lo;
    }
}

// ---------------------------------------------------------------- phase A
// Grid (32, BATCH), 4 waves. Pyramid rows: stride 40 ushorts (80 B).
__global__ __launch_bounds__(256) void wn_fuseA(
    const float* __restrict__ x, const float* __restrict__ in_w,
    const float* __restrict__ in_b,
    const ushort* __restrict__ Wd, const ushort* __restrict__ Wr,
    const float* __restrict__ dil_b, const float* __restrict__ res_b,
    ushort* __restrict__ c6h, ushort* __restrict__ c6l,
    float* __restrict__ gTL)
{
    __shared__ __align__(16) ushort pingH[96 * 40], pingL[96 * 40];
    __shared__ __align__(16) ushort pongH[95 * 40], pongL[95 * 40];
    __shared__ __align__(16) ushort sGH[4][16 * 40], sGL[4][16 * 40];
    float* xs = (float*)pongH;                   // 7680 B, fits pongH

    const int tid = threadIdx.x, lane = tid & 63, w = tid >> 6;
    const int nl = lane & 15, o = lane >> 4;
    const int cc = blockIdx.x, b = blockIdx.y;
    const int t6a = 6174 + cc * 64, a0 = t6a - 31;
    const short8 z8 = {0, 0, 0, 0, 0, 0, 0, 0};
    const short8 I0 = ident_frag(nl, o, 0);
    const short8 I1 = ident_frag(nl, o, 1);

    // ---- stage x (96 pos x 16 ch fp32)
    for (int i = tid; i < 384; i += 256) {
        const int p = i >> 2, c4 = (i & 3) * 4;
        const int t = a0 + p;
        float4 v = make_float4(0.f, 0.f, 0.f, 0.f);
        if (t <= 8191) v = *(const float4*)&x[((size_t)b * 8192 + t) * 16 + c4];
        *(float4*)&xs[p * 20 + c4] = v;
    }
    __syncthreads();

    // ---- in_conv -> ping (hi/lo)
    {
        const int c = tid & 31, pg = tid >> 5;
        float wr[16];
        #pragma unroll
        for (int f = 0; f < 16; ++f) wr[f] = in_w[c * 16 + f];
        const float bias = in_b[c];
        #pragma unroll
        for (int q = 0; q < 12; ++q) {
            const int p = pg + 8 * q;
            float acc = bias;
            #pragma unroll
            for (int f4 = 0; f4 < 4; ++f4) {
                const float4 xv = *(const float4*)&xs[p * 20 + f4 * 4];
                acc += wr[f4*4]*xv.x + wr[f4*4+1]*xv.y
                     + wr[f4*4+2]*xv.z + wr[f4*4+3]*xv.w;
            }
            ushort hh, hl;
            split2(acc, hh, hl);
            pingH[p * 40 + c] = hh;
            pingL[p * 40 + c] = hl;
        }
    }
    __syncthreads();   // xs dead; pong free for l0 output

    for (int l = 0; l < 6; ++l) {
        const ushort* HiH = (l & 1) ? pongH : pingH;
        const ushort* HiL = (l & 1) ? pongL : pingL;
        ushort* HoH = (l & 1) ? pingH : pongH;
        ushort* HoL = (l & 1) ? pingL : pongL;
        const int nIn  = (l == 0) ? 96 : (192 >> l) - 1;
        const int nOut = (192 >> (l + 1)) - 1;      // 95,47,23,11,5,2
        const int nT   = (nOut + 15) >> 4;
        const int sO   = 1 << l;
        const int aO   = a0 + sO - 1;
        const int bOff = (l == 0) ? 1 : (sO >> 1);
        const int rmx  = (l == 0) ? 8191 : TLAST;
        const int first = (l == 0);
        const int capRem = TLAST - aO;
        const int capIdx = ((capRem % sO) == 0) ? (capRem / sO) : -1;

        const ushort* pd = Wd + (size_t)l * 8192;
        const ushort* pr = Wr + (size_t)l * 2048;
        float dbg[2], dbf[2], rbv[2];
        #pragma unroll
        for (int nt = 0; nt < 2; ++nt) {
            dbg[nt] = dil_b[l * 64 + nl + 16 * nt];
            dbf[nt] = dil_b[l * 64 + nl + 16 * nt + 32];
            rbv[nt] = res_b[l * 32 + nl + 16 * nt];
        }

        for (int tt = w; tt < nT; tt += 4) {
            const int joF = tt * 16 + nl;
            const int j0 = imin(first ? joF : 2 * joF, nIn - 1);
            const int j1 = imin(first ? joF + 1 : 2 * joF + 2, nIn - 1);
            const int jr = imin(first ? joF + 1 : 2 * joF + 1, nIn - 1);
            const bool zB = (aO + joF * sO + bOff) > rmx;

            // ---- residual rows + identity-MFMA into res accumulator init
            const short8 RhA = *(const short8*)&HiH[jr * 40 + 8 * o];
            const short8 RlA = *(const short8*)&HiL[jr * 40 + 8 * o];
            f32x4 aR[2];
            aR[0] = (f32x4){rbv[0], rbv[0], rbv[0], rbv[0]};
            aR[1] = (f32x4){rbv[1], rbv[1], rbv[1], rbv[1]};
            aR[0] = MFMA(RhA, I0, aR[0]);
            aR[0] = MFMA(RlA, I0, aR[0]);
            aR[1] = MFMA(RhA, I1, aR[1]);
            aR[1] = MFMA(RlA, I1, aR[1]);

            short8 Ah[2], Al[2];
            Ah[0] = *(const short8*)&HiH[j0 * 40 + 8 * o];
            Al[0] = *(const short8*)&HiL[j0 * 40 + 8 * o];
            if (zB) { Ah[1] = z8; Al[1] = z8; }
            else {
                Ah[1] = *(const short8*)&HiH[j1 * 40 + 8 * o];
                Al[1] = *(const short8*)&HiL[j1 * 40 + 8 * o];
            }

            // ---- gate/filt GEMM, bias in C-init
            f32x4 acc[4];
            #pragma unroll
            for (int nt = 0; nt < 2; ++nt) {
                acc[nt]     = (f32x4){dbg[nt], dbg[nt], dbg[nt], dbg[nt]};
                acc[nt + 2] = (f32x4){dbf[nt], dbf[nt], dbf[nt], dbf[nt]};
            }
            #pragma unroll
            for (int kt = 0; kt < 2; ++kt)
                #pragma unroll
                for (int nt = 0; nt < 4; ++nt) {
                    const int base = ((kt * 4 + nt) * 2) * 512 + lane * 8;
                    const short8 Bh = *(const short8*)&pd[base];
                    const short8 Bl = *(const short8*)&pd[base + 512];
                    acc[nt] = MFMA(Ah[kt], Bh, acc[nt]);
                    acc[nt] = MFMA(Ah[kt], Bl, acc[nt]);
                    acc[nt] = MFMA(Al[kt], Bh, acc[nt]);
                }

            float gv[8];
            #pragma unroll
            for (int nt = 0; nt < 2; ++nt)
                #pragma unroll
                for (int r = 0; r < 4; ++r) {
                    const float g = act_native(acc[nt][r], acc[nt + 2][r]);
                    gv[nt * 4 + r] = g;
                    const int ml = 4 * o + r, n = nl + 16 * nt;
                    ushort gh16, gl16;
                    split2(g, gh16, gl16);
                    sGH[w][ml * 40 + n] = gh16;
                    sGL[w][ml * 40 + n] = gl16;
                }
            if (capIdx >= tt * 16 && capIdx < imin(tt * 16 + 16, nOut)) {
                #pragma unroll
                for (int nt = 0; nt < 2; ++nt)
                    #pragma unroll
                    for (int r = 0; r < 4; ++r)
                        if (tt * 16 + 4 * o + r == capIdx)
                            gTL[((size_t)l * BATCH + b) * 32 + nl + 16 * nt] =
                                gv[nt * 4 + r];
            }

            // ---- res GEMM (residual+bias already in aR)
            const short8 gh = *(const short8*)&sGH[w][nl * 40 + 8 * o];
            const short8 gl = *(const short8*)&sGL[w][nl * 40 + 8 * o];
            #pragma unroll
            for (int nt = 0; nt < 2; ++nt) {
                const int base = (nt * 2) * 512 + lane * 8;
                const short8 Rh = *(const short8*)&pr[base];
                const short8 Rl = *(const short8*)&pr[base + 512];
                aR[nt] = MFMA(gh, Rh, aR[nt]);
                aR[nt] = MFMA(gh, Rl, aR[nt]);
                aR[nt] = MFMA(gl, Rh, aR[nt]);
            }
            #pragma unroll
            for (int nt = 0; nt < 2; ++nt)
                #pragma unroll
                for (int r = 0; r < 4; ++r) {
                    const int joE = tt * 16 + 4 * o + r;
                    if (joE < nOut) {
                        const int n = nl + 16 * nt;
                        ushort hh, hl;
                        split2(aR[nt][r], hh, hl);
                        HoH[joE * 40 + n] = hh;
                        HoL[joE * 40 + n] = hl;
                        if (l == 5 && joE < 2) {
                            const size_t go = ((size_t)b * 64 + cc * 2 + joE) * 32 + n;
                            c6h[go] = hh;
                            c6l[go] = hl;
                        }
                    }
                }
        }
        __syncthreads();
    }
}

// ---------------------------------------------------------------- fuseB tile
__device__ __forceinline__ void layer_tile1(
    const ushort* __restrict__ HiH, const ushort* __restrict__ HiL,
    ushort* __restrict__ HoH, ushort* __restrict__ HoL,
    const ushort* __restrict__ pd, const ushort* __restrict__ pr,
    const float* __restrict__ db, const float* __restrict__ rb,
    float* __restrict__ gout, ushort* __restrict__ sGH, ushort* __restrict__ sGL,
    int tt, int nIn, int nOut, int sO, int aO, int bOff,
    int lane, int nl, int o, int doRes)
{
    const short8 z8 = {0,0,0,0,0,0,0,0};
    const int joF = tt * 16 + nl;
    const int j0 = imin(2 * joF, nIn - 1);
    const int j1 = imin(2 * joF + 2, nIn - 1);
    const int jr = imin(2 * joF + 1, nIn - 1);
    const bool zB = (aO + joF * sO + bOff) > TLAST;

    float dbg[2], dbf[2], rbv[2];
    #pragma unroll
    for (int nt = 0; nt < 2; ++nt) {
        dbg[nt] = db[nl + 16 * nt];
        dbf[nt] = db[nl + 16 * nt + 32];
        rbv[nt] = rb[nl + 16 * nt];
    }

    // residual via identity-MFMA
    const short8 I0 = ident_frag(nl, o, 0);
    const short8 I1 = ident_frag(nl, o, 1);
    const short8 RhA = *(const short8*)&HiH[jr * 40 + 8 * o];
    const short8 RlA = *(const short8*)&HiL[jr * 40 + 8 * o];
    f32x4 aR[2];
    aR[0] = (f32x4){rbv[0], rbv[0], rbv[0], rbv[0]};
    aR[1] = (f32x4){rbv[1], rbv[1], rbv[1], rbv[1]};
    aR[0] = MFMA(RhA, I0, aR[0]);
    aR[0] = MFMA(RlA, I0, aR[0]);
    aR[1] = MFMA(RhA, I1, aR[1]);
    aR[1] = MFMA(RlA, I1, aR[1]);

    short8 Ah[2], Al[2];
    Ah[0] = *(const short8*)&HiH[j0 * 40 + 8 * o];
    Al[0] = *(const short8*)&HiL[j0 * 40 + 8 * o];
    if (zB) { Ah[1] = z8; Al[1] = z8; }
    else {
        Ah[1] = *(const short8*)&HiH[j1 * 40 + 8 * o];
        Al[1] = *(const short8*)&HiL[j1 * 40 + 8 * o];
    }

    f32x4 acc[4];
    #pragma unroll
    for (int nt = 0; nt < 2; ++nt) {
        acc[nt]     = (f32x4){dbg[nt], dbg[nt], dbg[nt], dbg[nt]};
        acc[nt + 2] = (f32x4){dbf[nt], dbf[nt], dbf[nt], dbf[nt]};
    }
    #pragma unroll
    for (int kt = 0; kt < 2; ++kt)
        #pragma unroll
        for (int nt = 0; nt < 4; ++nt) {
            const int base = ((kt * 4 + nt) * 2) * 512 + lane * 8;
            const short8 Bh = *(const short8*)&pd[base];
            const short8 Bl = *(const short8*)&pd[base + 512];
            acc[nt] = MFMA(Ah[kt], Bh, acc[nt]);
            acc[nt] = MFMA(Ah[kt], Bl, acc[nt]);
            acc[nt] = MFMA(Al[kt], Bh, acc[nt]);
        }

    const int capRem = TLAST - aO;
    const int capIdx = ((capRem % sO) == 0) ? (capRem / sO) : -1;
    float gv[8];
    #pragma unroll
    for (int nt = 0; nt < 2; ++nt)
        #pragma unroll
        for (int r = 0; r < 4; ++r) {
            const float g = act_native(acc[nt][r], acc[nt + 2][r]);
            gv[nt * 4 + r] = g;
            const int ml = 4 * o + r, n = nl + 16 * nt;
            ushort gh16, gl16;
            split2(g, gh16, gl16);
            sGH[ml * 40 + n] = gh16;
            sGL[ml * 40 + n] = gl16;
        }
    if (capIdx >= tt * 16 && capIdx < imin(tt * 16 + 16, nOut)) {
        #pragma unroll
        for (int nt = 0; nt < 2; ++nt)
            #pragma unroll
            for (int r = 0; r < 4; ++r)
                if (tt * 16 + 4 * o + r == capIdx)
                    gout[nl + 16 * nt] = gv[nt * 4 + r];
    }

    if (doRes) {
        const short8 gh = *(const short8*)&sGH[nl * 40 + 8 * o];
        const short8 gl = *(const short8*)&sGL[nl * 40 + 8 * o];
        #pragma unroll
        for (int nt = 0; nt < 2; ++nt) {
            const int base = (nt * 2) * 512 + lane * 8;
            const short8 Rh = *(const short8*)&pr[base];
            const short8 Rl = *(const short8*)&pr[base + 512];
            aR[nt] = MFMA(gh, Rh, aR[nt]);
            aR[nt] = MFMA(gh, Rl, aR[nt]);
            aR[nt] = MFMA(gl, Rh, aR[nt]);
        }
        #pragma unroll
        for (int nt = 0; nt < 2; ++nt)
            #pragma unroll
            for (int r = 0; r < 4; ++r) {
                const int joE = tt * 16 + 4 * o + r;
                if (joE < nOut) {
                    const int n = nl + 16 * nt;
                    ushort hh, hl;
                    split2(aR[nt][r], hh, hl);
                    HoH[joE * 40 + n] = hh;
                    HoL[joE * 40 + n] = hl;
                }
            }
    }
}

// ---------------------------------------------------------------- phase B
__global__ __launch_bounds__(256) void wn_fuseB(
    const ushort* __restrict__ c6h, const ushort* __restrict__ c6l,
    const ushort* __restrict__ Wd, const ushort* __restrict__ Wr,
    const float* __restrict__ dil_b, const float* __restrict__ res_b,
    const float* __restrict__ gTL,
    const float* __restrict__ sw, const float* __restrict__ sb,
    const float* __restrict__ f1w, const float* __restrict__ f1b,
    const float* __restrict__ f2w, const float* __restrict__ f2b,
    float* __restrict__ out)
{
    __shared__ __align__(16) ushort HAh[64 * 40], HAl[64 * 40];
    __shared__ __align__(16) ushort HBh[32 * 40], HBl[32 * 40];
    __shared__ __align__(16) ushort sG2H[2][16 * 40], sG2L[2][16 * 40];
    __shared__ float gcap[6 * 32];
    __shared__ float psum[4][32];
    __shared__ float hd[64];

    const int tid = threadIdx.x, lane = tid & 63, w = tid >> 6;
    const int nl = lane & 15, o = lane >> 4;
    const int b = blockIdx.x;

    for (int i = tid; i < 256; i += 256) {
        const int row = i >> 2, c8 = (i & 3) * 8;
        *(short8*)&HAh[row * 40 + c8] = *(const short8*)&c6h[((size_t)b * 64 + row) * 32 + c8];
        *(short8*)&HAl[row * 40 + c8] = *(const short8*)&c6l[((size_t)b * 64 + row) * 32 + c8];
    }
    __syncthreads();

    if (w < 2) {
        layer_tile1(HAh, HAl, HBh, HBl, Wd + 6 * 8192, Wr + 6 * 2048,
                    dil_b + 6 * 64, res_b + 6 * 32,
                    gcap, sG2H[w], sG2L[w],
                    w, 64, 32, 64, 6206, 32, lane, nl, o, 1);
    }
    __syncthreads();

    if (w == 0) {
        for (int ll = 1; ll < 6; ++ll) {
            const int l = ll + 6;
            const ushort* HiH = (ll & 1) ? HBh : HAh;
            const ushort* HiL = (ll & 1) ? HBl : HAl;
            ushort* HoH = (ll & 1) ? HAh : HBh;
            ushort* HoL = (ll & 1) ? HAl : HBl;
            const int sO = 64 << ll;
            layer_tile1(HiH, HiL, HoH, HoL,
                        Wd + (size_t)l * 8192, Wr + (size_t)l * 2048,
                        dil_b + l * 64, res_b + l * 32,
                        gcap + ll * 32, sG2H[0], sG2L[0],
                        0, 64 >> ll, 32 >> ll, sO, 6142 + sO, sO >> 1,
                        lane, nl, o, (ll < 5) ? 1 : 0);
        }
    }
    __syncthreads();

    if (lane < 32) {
        const int c = lane;
        float part = 0.f;
        #pragma unroll
        for (int j = 0; j < 3; ++j) {
            const int l2 = 3 * w + j;
            float a = sb[l2 * 32 + c];
            const float* swr = sw + l2 * 1024 + c * 32;
            const float* gvp = (l2 < 6) ? (gTL + ((size_t)l2 * BATCH + b) * 32)
                                        : (gcap + (l2 - 6) * 32);
            #pragma unroll
            for (int ic = 0; ic < 32; ++ic) a += swr[ic] * gvp[ic];
            part += a;
        }
        psum[w][c] = part;
    }
    __syncthreads();

    if (w == 0 && lane < 32)
        hd[lane] = fmaxf(psum[0][lane] + psum[1][lane] + psum[2][lane] + psum[3][lane], 0.f);
    if (w == 0 && lane < 32) {
        float z = f1b[lane];
        #pragma unroll
        for (int ic = 0; ic < 32; ++ic) z += f1w[lane * 32 + ic] * hd[ic];
        hd[32 + lane] = fmaxf(z, 0.f);
    }
    if (w == 0 && lane == 0) {
        float o2 = f2b[0];
        #pragma unroll
        for (int ic = 0; ic < 32; ++ic) o2 += f2w[ic] * hd[32 + ic];
        out[b] = o2;
    }
}

// ---------------------------------------------------------------- launch
extern "C" void kernel_launch(void* const* d_in, const int* in_sizes, int n_in,
                              void* d_out, int out_size, void* d_ws, size_t ws_size,
                              hipStream_t stream)
{
    const float* x      = (const float*)d_in[0];
    const float* in_w   = (const float*)d_in[1];
    const float* in_b   = (const float*)d_in[2];
    const float* dil_w  = (const float*)d_in[3];
    const float* dil_b  = (const float*)d_in[4];
    const float* skip_w = (const float*)d_in[5];
    const float* skip_b = (const float*)d_in[6];
    const float* res_w  = (const float*)d_in[7];
    const float* res_b  = (const float*)d_in[8];
    const float* f1_w   = (const float*)d_in[9];
    const float* f1_b   = (const float*)d_in[10];
    const float* f2_w   = (const float*)d_in[11];
    const float* f2_b   = (const float*)d_in[12];

    char* p = (char*)d_ws;
    ushort* Wd  = (ushort*)p; p += 12 * 8192 * 2;
    ushort* Wr  = (ushort*)p; p += 12 * 2048 * 2;
    ushort* c6h = (ushort*)p; p += 32 * 64 * 32 * 2;
    ushort* c6l = (ushort*)p; p += 32 * 64 * 32 * 2;
    float*  gTL = (float*)p;

    wn_prep<<<dim3(240), dim3(256), 0, stream>>>(dil_w, res_w, Wd, Wr);

    wn_fuseA<<<dim3(32, BATCH), dim3(256), 0, stream>>>(
        x, in_w, in_b, Wd, Wr, dil_b, res_b, c6h, c6l, gTL);

    wn_fuseB<<<dim3(BATCH), dim3(256), 0, stream>>>(
        c6h, c6l, Wd, Wr, dil_b, res_b, gTL,
        skip_w, skip_b, f1_w, f1_b, f2_w, f2_b, (float*)d_out);
}